// Round 4
// baseline (577.519 us; speedup 1.0000x reference)
//
#include <hip/hip_runtime.h>
#include <hip/hip_bf16.h>

#define NN 20000
#define IN 128
#define HH 2
#define DD 32
#define HD 64
#define KK 3
#define RR 5
#define EE 320000
#define NEG 0.2f

#define PADK 136

typedef short v8s __attribute__((ext_vector_type(8)));
typedef float v4f __attribute__((ext_vector_type(4)));

__device__ __forceinline__ ushort f2b(float f) {
    unsigned u = __float_as_uint(f);
    unsigned r = (u + 0x7fff + ((u >> 16) & 1)) >> 16;   // RNE
    return (ushort)r;
}
__device__ __forceinline__ ushort f2h(float f) {
    _Float16 h = (_Float16)f;
    return __builtin_bit_cast(ushort, h);
}
__device__ __forceinline__ float h2f(ushort u) {
    _Float16 h = __builtin_bit_cast(_Float16, u);
    return (float)h;
}

// ---------------------------------------------------------------------------
// K0a: h (fp32) -> hb (bf16) for MFMA A
// ---------------------------------------------------------------------------
__global__ __launch_bounds__(256) void cvt_h_kernel(
    const float* __restrict__ h, ushort* __restrict__ hb)
{
    int i = blockIdx.x * 256 + threadIdx.x;
    if (i >= NN * IN / 4) return;
    float4 v = ((const float4*)h)[i];
    ((ushort4*)hb)[i] = make_ushort4(f2b(v.x), f2b(v.y), f2b(v.z), f2b(v.w));
}

// ---------------------------------------------------------------------------
// K0b: weights -> wb bf16, transposed+fused: wb[r][col][k], col<64=fc else res
// ---------------------------------------------------------------------------
__global__ __launch_bounds__(256) void cvt_w_kernel(
    const float* __restrict__ fcw, const float* __restrict__ resw,
    ushort* __restrict__ wb)
{
    int i = blockIdx.x * 256 + threadIdx.x;
    if (i >= RR * 128 * IN) return;
    int k = i & 127;
    int c = (i >> 7) & 127;
    int r = i >> 14;
    float v = (c < HD) ? fcw[(r * IN + k) * HD + c] : resw[(r * IN + k) * HD + (c - HD)];
    wb[i] = f2b(v);
}

// ---------------------------------------------------------------------------
// K1: projection via bf16 MFMA; emits fp32 hop0 + res and fp16 table t0.
// ---------------------------------------------------------------------------
__global__ __launch_bounds__(256) void proj_mfma(
    const ushort* __restrict__ hb, const ushort* __restrict__ wb,
    float* __restrict__ hops, float* __restrict__ res,
    ushort* __restrict__ t0)
{
    __shared__ ushort As[64 * PADK];
    __shared__ ushort Bs[128 * PADK];
    int bx = blockIdx.x;
    int r = bx / 313;
    int tile = bx - r * 313;
    int n0 = tile * 64;
    int tid = threadIdx.x;

    #pragma unroll
    for (int i = 0; i < 4; i++) {
        int c = tid + 256 * i;
        int row = c >> 4;
        int off = (c & 15) * 8;
        int gn = n0 + row;
        uint4 v = make_uint4(0, 0, 0, 0);
        if (gn < NN) v = *(const uint4*)&hb[gn * IN + off];
        *(uint4*)&As[row * PADK + off] = v;
    }
    const ushort* wr = wb + (size_t)r * 128 * IN;
    #pragma unroll
    for (int i = 0; i < 8; i++) {
        int c = tid + 256 * i;
        int row = c >> 4;
        int off = (c & 15) * 8;
        *(uint4*)&Bs[row * PADK + off] = *(const uint4*)&wr[row * IN + off];
    }
    __syncthreads();

    int w = tid >> 6, lane = tid & 63;
    int lm = lane & 15, lq = lane >> 4;

    v4f acc[4][2];
    #pragma unroll
    for (int mt = 0; mt < 4; mt++)
        #pragma unroll
        for (int nt = 0; nt < 2; nt++) acc[mt][nt] = (v4f){0.f, 0.f, 0.f, 0.f};

    const ushort* Ab = &As[lm * PADK + lq * 8];
    const ushort* Bb = &Bs[(w * 32 + lm) * PADK + lq * 8];

    #pragma unroll
    for (int ks = 0; ks < 4; ks++) {
        v8s a[4], b[2];
        #pragma unroll
        for (int mt = 0; mt < 4; mt++) a[mt] = *(const v8s*)(Ab + mt * 16 * PADK + ks * 32);
        #pragma unroll
        for (int nt = 0; nt < 2; nt++) b[nt] = *(const v8s*)(Bb + nt * 16 * PADK + ks * 32);
        #pragma unroll
        for (int mt = 0; mt < 4; mt++)
            #pragma unroll
            for (int nt = 0; nt < 2; nt++)
                acc[mt][nt] = __builtin_amdgcn_mfma_f32_16x16x32_bf16(a[mt], b[nt], acc[mt][nt], 0, 0, 0);
    }

    int colbase = w * 32 + lm;
    #pragma unroll
    for (int mt = 0; mt < 4; mt++) {
        #pragma unroll
        for (int nt = 0; nt < 2; nt++) {
            int col = colbase + nt * 16;
            #pragma unroll
            for (int p = 0; p < 4; p++) {
                int node = n0 + mt * 16 + lq * 4 + p;
                if (node < NN) {
                    float v = acc[mt][nt][p];
                    if (col < HD) {
                        hops[((size_t)(r * 4) * NN + node) * HD + col] = v;
                        t0[((size_t)r * NN + node) * HD + col] = f2h(v);
                    } else {
                        res[((size_t)r * NN + node) * HD + (col - HD)] = v;
                    }
                }
            }
        }
    }
}

// ---------------------------------------------------------------------------
// K1b: per-node attention scalars el/er
// ---------------------------------------------------------------------------
__global__ __launch_bounds__(256) void attn_node_kernel(
    const float* __restrict__ hops, const float* __restrict__ attn_l,
    const float* __restrict__ attn_r, float* __restrict__ el,
    float* __restrict__ er)
{
    int idx = blockIdx.x * 256 + threadIdx.x;
    if (idx >= RR * NN * HH) return;
    int h_ = idx & 1;
    int n = (idx >> 1) % NN;
    int r = idx / (NN * HH);
    const float4* x = (const float4*)(hops + ((size_t)(r * 4) * NN + n) * HD + h_ * DD);
    const float4* al = (const float4*)(attn_l + (r * HH + h_) * DD);
    const float4* ar = (const float4*)(attn_r + (r * HH + h_) * DD);
    float sl = 0.f, sr = 0.f;
    #pragma unroll
    for (int d = 0; d < 8; d++) {
        float4 v = x[d], a = al[d], b = ar[d];
        sl += v.x * a.x + v.y * a.y + v.z * a.z + v.w * a.w;
        sr += v.x * b.x + v.y * b.y + v.z * b.z + v.w * b.w;
    }
    el[idx] = sl;
    er[idx] = sr;
}

// ---------------------------------------------------------------------------
// K2: histogram of dst per relation
// ---------------------------------------------------------------------------
__global__ __launch_bounds__(256) void count_kernel(
    const int* __restrict__ dst, int* __restrict__ counts)
{
    int idx = blockIdx.x * 256 + threadIdx.x;
    if (idx >= RR * EE) return;
    int r = idx / EE;
    atomicAdd(&counts[r * NN + dst[idx]], 1);
}

// ---------------------------------------------------------------------------
// K3: per-relation exclusive scan
// ---------------------------------------------------------------------------
__global__ __launch_bounds__(256) void scan_kernel(
    const int* __restrict__ counts, int* __restrict__ rowp,
    int* __restrict__ cursor)
{
    __shared__ int wsum[4];
    __shared__ int carry;
    int r = blockIdx.x;
    int tid = threadIdx.x;
    int lane = tid & 63, w = tid >> 6;
    if (tid == 0) { carry = 0; rowp[r * (NN + 1)] = 0; }
    __syncthreads();
    const int4* c4 = (const int4*)(counts + r * NN);
    int* rp = rowp + r * (NN + 1);
    int* cur = cursor + r * NN;
    for (int base = 0; base < NN / 4; base += 256) {
        int i4 = base + tid;
        int4 v = (i4 < NN / 4) ? c4[i4] : make_int4(0, 0, 0, 0);
        int s = v.x + v.y + v.z + v.w;
        int x = s;
        #pragma unroll
        for (int off = 1; off < 64; off <<= 1) {
            int t = __shfl_up(x, off, 64);
            if (lane >= off) x += t;
        }
        if (lane == 63) wsum[w] = x;
        __syncthreads();
        int add = carry;
        for (int j = 0; j < w; j++) add += wsum[j];
        int px = add + x - s;
        if (i4 < NN / 4) {
            int e0 = i4 * 4;
            int p1 = px + v.x, p2 = p1 + v.y, p3 = p2 + v.z, p4 = p3 + v.w;
            cur[e0] = px;     rp[e0 + 1] = p1;
            cur[e0 + 1] = p1; rp[e0 + 2] = p2;
            cur[e0 + 2] = p2; rp[e0 + 3] = p3;
            cur[e0 + 3] = p3; rp[e0 + 4] = p4;
        }
        __syncthreads();
        if (tid == 255) carry += wsum[0] + wsum[1] + wsum[2] + wsum[3];
        __syncthreads();
    }
}

// ---------------------------------------------------------------------------
// K4: scatter only src (4 B) into CSR slots
// ---------------------------------------------------------------------------
__global__ __launch_bounds__(256) void scatter_kernel(
    const int* __restrict__ src, const int* __restrict__ dst,
    int* __restrict__ cursor, int* __restrict__ csrS)
{
    int idx = blockIdx.x * 256 + threadIdx.x;
    if (idx >= RR * EE) return;
    int r = idx / EE;
    int s = src[idx], d = dst[idx];
    int pos = atomicAdd(cursor + r * NN + d, 1);
    csrS[(size_t)r * EE + pos] = s;
}

// ---------------------------------------------------------------------------
// K5: per-dst softmax -> edge records {src, half2(w0,w1)}, sequential writes
// ---------------------------------------------------------------------------
__global__ __launch_bounds__(256) void alpha_kernel(
    const int* __restrict__ csrS, const int* __restrict__ rowp,
    const float* __restrict__ el, const float* __restrict__ er,
    uint2* __restrict__ csrE)
{
    int idx = blockIdx.x * 256 + threadIdx.x;
    if (idx >= RR * NN) return;
    int r = idx / NN;
    int n = idx - r * NN;
    int b = rowp[r * (NN + 1) + n];
    int e = rowp[r * (NN + 1) + n + 1];
    if (e <= b) return;
    const int* S = csrS + (size_t)r * EE;
    const float2* el2 = (const float2*)el + r * NN;
    float2 dr = ((const float2*)er)[r * NN + n];
    float m0 = -1e30f, m1 = -1e30f, s0 = 0.f, s1 = 0.f;
    for (int i = b; i < e; i++) {
        float2 a = el2[S[i]];
        float l0 = a.x + dr.x; l0 = l0 > 0.f ? l0 : NEG * l0;
        float l1 = a.y + dr.y; l1 = l1 > 0.f ? l1 : NEG * l1;
        float nm0 = fmaxf(m0, l0), nm1 = fmaxf(m1, l1);
        s0 = s0 * __expf(m0 - nm0) + __expf(l0 - nm0);
        s1 = s1 * __expf(m1 - nm1) + __expf(l1 - nm1);
        m0 = nm0; m1 = nm1;
    }
    float i0 = 1.f / fmaxf(s0, 1e-9f), i1 = 1.f / fmaxf(s1, 1e-9f);
    uint2* E = csrE + (size_t)r * EE;
    for (int i = b; i < e; i++) {
        int s = S[i];
        float2 a = el2[s];
        float l0 = a.x + dr.x; l0 = l0 > 0.f ? l0 : NEG * l0;
        float l1 = a.y + dr.y; l1 = l1 > 0.f ? l1 : NEG * l1;
        float w0 = __expf(l0 - m0) * i0;
        float w1 = __expf(l1 - m1) * i1;
        E[i] = make_uint2((unsigned)s, (unsigned)f2h(w0) | ((unsigned)f2h(w1) << 16));
    }
}

// ---------------------------------------------------------------------------
// K6: diffusion hop. Wave per (r,dst); fp16 gather, fp32 accumulate.
// hout points at hops + k*NN*HD (relation stride 4*NN*HD handled inside).
// ---------------------------------------------------------------------------
__global__ __launch_bounds__(256) void hop_kernel(
    const ushort* __restrict__ tin, float* __restrict__ hops_k,
    ushort* __restrict__ tout, const uint2* __restrict__ csrE,
    const int* __restrict__ rowp)
{
    int w = (blockIdx.x * 256 + threadIdx.x) >> 6;
    if (w >= RR * NN) return;
    int lane = threadIdx.x & 63;
    int sh = (lane >> 5) * 16;
    int r = w / NN;
    int n = w - r * NN;
    int b = rowp[r * (NN + 1) + n];
    int e = rowp[r * (NN + 1) + n + 1];
    const ushort* T = tin + (size_t)r * NN * HD;
    const uint2* E = csrE + (size_t)r * EE;
    float a0 = 0.f, a1 = 0.f, a2 = 0.f, a3 = 0.f;
    int i = b;
    for (; i + 3 < e; i += 4) {
        uint2 e0 = E[i], e1 = E[i + 1], e2 = E[i + 2], e3 = E[i + 3];
        a0 += h2f((ushort)(e0.y >> sh)) * h2f(T[(size_t)e0.x * HD + lane]);
        a1 += h2f((ushort)(e1.y >> sh)) * h2f(T[(size_t)e1.x * HD + lane]);
        a2 += h2f((ushort)(e2.y >> sh)) * h2f(T[(size_t)e2.x * HD + lane]);
        a3 += h2f((ushort)(e3.y >> sh)) * h2f(T[(size_t)e3.x * HD + lane]);
    }
    for (; i < e; i++) {
        uint2 e0 = E[i];
        a0 += h2f((ushort)(e0.y >> sh)) * h2f(T[(size_t)e0.x * HD + lane]);
    }
    float acc = (a0 + a1) + (a2 + a3);
    __builtin_nontemporal_store(acc, &hops_k[((size_t)(r * 4) * NN + n) * HD + lane]);
    if (tout) tout[((size_t)r * NN + n) * HD + lane] = f2h(acc);
}

// ---------------------------------------------------------------------------
// K7: hop-norm + hop attention + residual + relation combine + head mean
// ---------------------------------------------------------------------------
__device__ __forceinline__ float red32(float v) {
    v += __shfl_xor(v, 16, 64);
    v += __shfl_xor(v, 8, 64);
    v += __shfl_xor(v, 4, 64);
    v += __shfl_xor(v, 2, 64);
    v += __shfl_xor(v, 1, 64);
    return v;
}

__global__ __launch_bounds__(256) void final_kernel(
    const float* __restrict__ hops, const float* __restrict__ res,
    const float* __restrict__ hal, const float* __restrict__ har,
    const float* __restrict__ w_rel, const float* __restrict__ b_rel,
    float* __restrict__ out)
{
    int w = (blockIdx.x * 256 + threadIdx.x) >> 6;
    if (w >= NN) return;
    int lane = threadIdx.x & 63;
    int h_ = lane >> 5;
    int d_ = lane & 31;
    float acc = 0.f;
    #pragma unroll
    for (int r = 0; r < RR; r++) {
        float wr = b_rel[r];
        #pragma unroll
        for (int j = 0; j < RR; j++) wr += w_rel[r * RR + j];
        float halv = hal[(r * HH + h_) * DD + d_];
        float harv = har[(r * HH + h_) * DD + d_];
        float vn[4], lg[4];
        float hr = 0.f;
        #pragma unroll
        for (int kk = 0; kk < 4; kk++) {
            float v = hops[((size_t)(r * 4 + kk) * NN + w) * HD + lane];
            float sq = red32(v * v);
            float inv = 1.f / fmaxf(sqrtf(sq), 1e-9f);
            v *= inv;
            vn[kk] = v;
            lg[kk] = red32(v * halv);
            if (kk == 0) hr = red32(v * harv);
        }
        float mx = -1e30f;
        #pragma unroll
        for (int kk = 0; kk < 4; kk++) {
            float l = lg[kk] + hr;
            l = l > 0.f ? l : NEG * l;
            lg[kk] = l;
            mx = fmaxf(mx, l);
        }
        float s = 0.f;
        #pragma unroll
        for (int kk = 0; kk < 4; kk++) { float ex = __expf(lg[kk] - mx); lg[kk] = ex; s += ex; }
        float o = 0.f;
        #pragma unroll
        for (int kk = 0; kk < 4; kk++) o += lg[kk] * vn[kk];
        o /= s;
        o += res[((size_t)r * NN + w) * HD + lane];
        acc += wr * o;
    }
    float other = __shfl_xor(acc, 32, 64);
    if (lane < 32) out[(size_t)w * DD + d_] = 0.5f * (acc + other);
}

// ---------------------------------------------------------------------------
extern "C" void kernel_launch(void* const* d_in, const int* in_sizes, int n_in,
                              void* d_out, int out_size, void* d_ws, size_t ws_size,
                              hipStream_t stream) {
    (void)in_sizes; (void)n_in; (void)out_size; (void)ws_size;
    const float* h     = (const float*)d_in[0];
    const int*   src   = (const int*)d_in[1];
    const int*   dst   = (const int*)d_in[2];
    const float* fcw   = (const float*)d_in[3];
    const float* resw  = (const float*)d_in[4];
    const float* atl   = (const float*)d_in[5];
    const float* atr   = (const float*)d_in[6];
    const float* hal   = (const float*)d_in[7];
    const float* har   = (const float*)d_in[8];
    const float* wrel  = (const float*)d_in[9];
    const float* brel  = (const float*)d_in[10];
    float* out = (float*)d_out;

    float* ws = (float*)d_ws;
    size_t off = 0;
    float* hops = ws + off;  off += (size_t)RR * 4 * NN * HD;
    float* res  = ws + off;  off += (size_t)RR * NN * HD;
    float* el   = ws + off;  off += (size_t)RR * NN * HH;
    float* er   = ws + off;  off += (size_t)RR * NN * HH;
    uint2* csrE = (uint2*)(ws + off);     off += (size_t)RR * EE * 2;
    int* csrS   = (int*)(ws + off);       off += (size_t)RR * EE;
    ushort* t0  = (ushort*)(ws + off);    off += (size_t)RR * NN * HD / 2;
    ushort* t1  = (ushort*)(ws + off);    off += (size_t)RR * NN * HD / 2;
    ushort* t2  = (ushort*)(ws + off);    off += (size_t)RR * NN * HD / 2;
    ushort* hb  = (ushort*)(ws + off);    off += (size_t)NN * IN / 2;
    ushort* wb  = (ushort*)(ws + off);    off += (size_t)RR * 128 * IN / 2;
    int* rowp   = (int*)(ws + off);  off += (size_t)RR * (NN + 1) + 3;
    int* cursor = (int*)(ws + off);  off += (size_t)RR * NN;
    int* counts = (int*)(ws + off);  off += (size_t)RR * NN;

    hipMemsetAsync(counts, 0, (size_t)RR * NN * sizeof(int), stream);

    cvt_h_kernel<<<(NN * IN / 4 + 255) / 256, 256, 0, stream>>>(h, hb);
    cvt_w_kernel<<<(RR * 128 * IN + 255) / 256, 256, 0, stream>>>(fcw, resw, wb);
    proj_mfma<<<313 * RR, 256, 0, stream>>>(hb, wb, hops, res, t0);
    attn_node_kernel<<<(RR * NN * HH + 255) / 256, 256, 0, stream>>>(hops, atl, atr, el, er);
    count_kernel<<<(RR * EE + 255) / 256, 256, 0, stream>>>(dst, counts);
    scan_kernel<<<RR, 256, 0, stream>>>(counts, rowp, cursor);
    scatter_kernel<<<(RR * EE + 255) / 256, 256, 0, stream>>>(src, dst, cursor, csrS);
    alpha_kernel<<<(RR * NN + 255) / 256, 256, 0, stream>>>(csrS, rowp, el, er, csrE);
    hop_kernel<<<(RR * NN + 3) / 4, 256, 0, stream>>>(t0, hops + (size_t)1 * NN * HD, t1, csrE, rowp);
    hop_kernel<<<(RR * NN + 3) / 4, 256, 0, stream>>>(t1, hops + (size_t)2 * NN * HD, t2, csrE, rowp);
    hop_kernel<<<(RR * NN + 3) / 4, 256, 0, stream>>>(t2, hops + (size_t)3 * NN * HD, nullptr, csrE, rowp);
    final_kernel<<<NN / 4, 256, 0, stream>>>(hops, res, hal, har, wrel, brel, out);
}